// Round 12
// baseline (233.485 us; speedup 1.0000x reference)
//
#include <hip/hip_runtime.h>

typedef __attribute__((ext_vector_type(8))) _Float16 f16x8;
typedef __attribute__((ext_vector_type(4))) float f32x4;

#define B_SZ   16
#define N_SEQ  4096
#define M_CTX  77
#define M_PAD  96
#define NH     8
#define NROWS  65536          // B_SZ * N_SEQ

__device__ __forceinline__ _Float16 f2h(float x) { return (_Float16)x; }

// async global->LDS, 16B per lane. dst = wave-uniform base; HW writes
// dst + lane*16. Source address is per-lane.
__device__ __forceinline__ void gload16(const void* g, void* l) {
    __builtin_amdgcn_global_load_lds(
        (const __attribute__((address_space(1))) unsigned int*)g,
        (__attribute__((address_space(3))) unsigned int*)l, 16, 0, 0);
}

#define BAR()    asm volatile("s_barrier" ::: "memory")
#define WAITV8() asm volatile("s_waitcnt vmcnt(8)" ::: "memory")
#define WAITV4() asm volatile("s_waitcnt vmcnt(4)" ::: "memory")
#define WAITV0() asm volatile("s_waitcnt vmcnt(0)" ::: "memory")

// ---- DPP 16-lane butterfly reductions (XOR masks {1,2,7,15} span 0..15) ----
template<int C>
__device__ __forceinline__ float dppf(float x) {
    union { float f; int i; } u, v;
    u.f = x;
    v.i = __builtin_amdgcn_mov_dpp(u.i, C, 0xF, 0xF, true);
    return v.f;
}
__device__ __forceinline__ float rmax16(float x) {
    x = fmaxf(x, dppf<0xB1>(x));
    x = fmaxf(x, dppf<0x4E>(x));
    x = fmaxf(x, dppf<0x141>(x));
    x = fmaxf(x, dppf<0x140>(x));
    return x;
}
__device__ __forceinline__ float rsum16(float x) {
    x += dppf<0xB1>(x);
    x += dppf<0x4E>(x);
    x += dppf<0x141>(x);
    x += dppf<0x140>(x);
    return x;
}

// ---------------------------------------------------------------------------
// convert_t: x fp32 -> xhT f16 in K-TILED layout [rb][kt][128][32]
// (xhT flat f16 idx = ((rb*16+kt)*128 + r)*32 + c, r=row&127, rb=row>>7,
//  kt=col>>5, c=col&31). Writes 1KB-contiguous per wave; reads 128B-aligned
//  line-granular chunks per row. Memory-bound ~201 MB.
// ---------------------------------------------------------------------------
__global__ __launch_bounds__(256)
void convert_t(const float* __restrict__ x, f16x8* __restrict__ xhT, int n8)
{
    int idx = blockIdx.x * 256 + threadIdx.x;
    int stride = gridDim.x * 256;
    for (int g = idx; g < n8; g += stride) {
        int c8 = g & 3;              // 8-col group within 32
        int r  = (g >> 2) & 127;
        int kt = (g >> 9) & 15;
        int rb = g >> 13;
        const float* a = x + ((size_t)(rb * 128 + r) * 512 + kt * 32 + c8 * 8);
        float4 f0 = *(const float4*)a;
        float4 f1 = *(const float4*)(a + 4);
        f16x8 o;
        o[0] = f2h(f0.x); o[1] = f2h(f0.y); o[2] = f2h(f0.z); o[3] = f2h(f0.w);
        o[4] = f2h(f1.x); o[5] = f2h(f1.y); o[6] = f2h(f1.z); o[7] = f2h(f1.w);
        xhT[g] = o;
    }
}

// ---------------------------------------------------------------------------
// prep: W [768][512] fp32 -> WT [512][768] f16 row-major (Wk, Wv only; used
// by kv_proj which reads contiguous 768-row slices). grid (16, 24, 2).
// ---------------------------------------------------------------------------
__global__ __launch_bounds__(256)
void prep(const float* __restrict__ Wk, const float* __restrict__ Wv,
          _Float16* __restrict__ WkT, _Float16* __restrict__ WvT)
{
    __shared__ float t[32][33];
    const float* W = blockIdx.z ? Wv : Wk;
    _Float16* WT   = blockIdx.z ? WvT : WkT;
    const int ky = blockIdx.y, nx = blockIdx.x;
    const int tr = threadIdx.x >> 5, tc = threadIdx.x & 31;
#pragma unroll
    for (int i = 0; i < 4; ++i) {
        int kr = tr + i * 8;
        t[kr][tc] = W[(size_t)(ky * 32 + kr) * 512 + nx * 32 + tc];
    }
    __syncthreads();
#pragma unroll
    for (int i = 0; i < 4; ++i) {
        int nr = tr + i * 8;
        WT[(size_t)(nx * 32 + nr) * 768 + ky * 32 + tc] = f2h(t[tc][nr]);
    }
}

// ---------------------------------------------------------------------------
// prep_bt: W [512][512] fp32 -> B-tiled f16 BTt[cb][kt][256][32]
// (element [n][k] at ((cb*16+kt)*256 + (n&255))*32 + (k&31), cb=n>>8,
//  kt=k>>5). Wq gets the 0.125 softmax scale folded in.
// grid (16 nx, 16 kt, 2 which); block 256.
// ---------------------------------------------------------------------------
__global__ __launch_bounds__(256)
void prep_bt(const float* __restrict__ Wq, const float* __restrict__ Wo,
             _Float16* __restrict__ WqTt, _Float16* __restrict__ WoTt)
{
    __shared__ float t[32][33];
    const float* W = blockIdx.z ? Wo : Wq;
    _Float16* WT   = blockIdx.z ? WoTt : WqTt;
    const float scale = blockIdx.z ? 1.0f : 0.125f;
    const int kt = blockIdx.y, nx = blockIdx.x;
    const int tr = threadIdx.x >> 5, tc = threadIdx.x & 31;
#pragma unroll
    for (int i = 0; i < 4; ++i) {
        int kr = tr + i * 8;
        t[kr][tc] = W[(size_t)(kt * 32 + kr) * 512 + nx * 32 + tc];
    }
    __syncthreads();
    const int cb = nx >> 3;                 // n-block 0..1
    const int nbase = (nx & 7) * 32;
#pragma unroll
    for (int i = 0; i < 4; ++i) {
        int nr = tr + i * 8;
        WT[((size_t)(cb * 16 + kt) * 256 + nbase + nr) * 32 + tc] =
            f2h(t[tc][nr] * scale);
    }
}

// ---------------------------------------------------------------------------
// kv_proj: writes K and V in BANK-SWIZZLED global layouts (unchanged, R3+):
//   Kswz[bh][m][ ((d>>3)^(m&7))*8 + (d&7) ]   m in 0..95 (zeros >= 77)
//   Vswz[bh][d][ ((m>>3)^(d&7))*8 + (m&7) ]   rows of 128 f16
// grid (8 h, 16 b, 2 kv); block 256 = 4 waves
// ---------------------------------------------------------------------------
__global__ __launch_bounds__(256)
void kv_proj(const float* __restrict__ cond, const _Float16* __restrict__ WkT,
             const _Float16* __restrict__ WvT, _Float16* __restrict__ Kswz,
             _Float16* __restrict__ Vswz)
{
    const int tid = threadIdx.x;
    const int l = tid & 63, w = tid >> 6;
    const int lrow = l & 15, lk = l >> 4;
    const int h = blockIdx.x, b = blockIdx.y, which = blockIdx.z;
    const _Float16* WT = which ? WvT : WkT;
    const float* cb = cond + (size_t)b * M_CTX * 768;

    f32x4 acc[5];
#pragma unroll
    for (int i = 0; i < 5; ++i)
#pragma unroll
        for (int e = 0; e < 4; ++e) acc[i][e] = 0.f;

    const int n = h * 64 + w * 16 + lrow;
    for (int kk = 0; kk < 24; ++kk) {
        f16x8 bfrag = *(const f16x8*)(WT + (size_t)n * 768 + kk * 32 + lk * 8);
#pragma unroll
        for (int rt = 0; rt < 5; ++rt) {
            int m = rt * 16 + lrow;
            f16x8 afrag;
#pragma unroll
            for (int j = 0; j < 8; ++j) afrag[j] = (_Float16)0.f;
            if (m < M_CTX) {
                const float* a = cb + (size_t)m * 768 + kk * 32 + lk * 8;
                float4 f0 = *(const float4*)a;
                float4 f1 = *(const float4*)(a + 4);
                afrag[0] = f2h(f0.x); afrag[1] = f2h(f0.y);
                afrag[2] = f2h(f0.z); afrag[3] = f2h(f0.w);
                afrag[4] = f2h(f1.x); afrag[5] = f2h(f1.y);
                afrag[6] = f2h(f1.z); afrag[7] = f2h(f1.w);
            }
            acc[rt] = __builtin_amdgcn_mfma_f32_16x16x32_f16(afrag, bfrag, acc[rt], 0, 0, 0);
        }
    }

    const int bh = b * NH + h;
    const int d = w * 16 + lrow;
    const int dhi = d >> 3, dlo = d & 7;
    if (which == 0) {
        _Float16* Kb = Kswz + (size_t)bh * (M_PAD * 64);
#pragma unroll
        for (int rt = 0; rt < 5; ++rt)
#pragma unroll
            for (int r = 0; r < 4; ++r) {
                int m = rt * 16 + lk * 4 + r;
                Kb[m * 64 + ((dhi ^ (m & 7)) * 8) + dlo] = f2h(acc[rt][r]);
            }
#pragma unroll
        for (int r = 0; r < 4; ++r) {
            int m = 80 + lk * 4 + r;
            Kb[m * 64 + ((dhi ^ (m & 7)) * 8) + dlo] = (_Float16)0.f;
        }
    } else {
        _Float16* Vb = Vswz + (size_t)bh * (64 * 128);
#pragma unroll
        for (int rt = 0; rt < 5; ++rt)
#pragma unroll
            for (int r = 0; r < 4; ++r) {
                int m = rt * 16 + lk * 4 + r;
                Vb[d * 128 + (((m >> 3) ^ dlo) * 8) + (m & 7)] = f2h(acc[rt][r]);
            }
#pragma unroll
        for (int r = 0; r < 4; ++r) {
            int m = 80 + lk * 4 + r;
            Vb[d * 128 + (((m >> 3) ^ dlo) * 8) + (m & 7)] = (_Float16)0.f;
        }
    }
}

// ---------------------------------------------------------------------------
// gemm_pipe: C = A @ B with A in K-tiled layout At[rb][kt][128][32] and B in
// B-tiled layout Bt[cb][kt][256][32] -- every stage gload16 reads 1KB
// CONTIGUOUS (convert-like DRAM pattern). R11-proven ring schedule: BM=BN=256,
// BK=32, 4 LDS slots (128KB), stage(kt+3) during kt, counted vmcnt (8/8/../
// 4/0 peeled tail -- fixes R11's latent kt=14/15 race). LDS is linear, reads
// are full 16-row x 64B spans => conflict-free without any swizzle.
// 8 waves (2M x 4N); 32 MFMA/kt in setprio(1).
// EMODE 0: C f16 head-major Qhm[h][row][64]; EMODE 1: C fp32 row-major +bias.
// grid 512 (=8*64 XCD-bijective); block 512.
// ---------------------------------------------------------------------------
template<int EMODE>
__global__ __launch_bounds__(512)
void gemm_pipe(const _Float16* __restrict__ At, const _Float16* __restrict__ Bt,
               void* __restrict__ Cv, const float* __restrict__ bias)
{
    __shared__ _Float16 L[4 * 16384];   // slot: [A 8192 f16 | B 8192 f16]

    const int bid = blockIdx.x;
    const int wg = (bid & 7) * 64 + (bid >> 3);
    const int rb0 = (wg >> 1) * 2;                 // 128-row chunk base
    const size_t row0 = (size_t)rb0 * 128;
    const int cb = wg & 1;                         // 256-col block

    const int tid = threadIdx.x;
    const int l = tid & 63, w = tid >> 6;          // 8 waves
    const int wy = w >> 2, wx = w & 3;             // 2M x 4N
    const int lrow = l & 15, lk = l >> 4;

    // staging: wave w covers A f16 [w*1024, w*1024+1024) of the 8192-f16 tile
    // (chunk w>>2 of the rb pair), and B likewise from one contiguous chunk.
    const int achunk = w >> 2;                     // 0 or 1 (rb0 / rb0+1)
    const int aoffw  = (w & 3) * 1024;             // within-chunk f16 offset
    const _Float16* a_base = At + ((size_t)(rb0 + achunk) * 16) * 4096 + aoffw + l * 8;
    const _Float16* b_base = Bt + ((size_t)cb * 16) * 8192 + w * 1024 + l * 8;

    auto stage = [&](int t) {
        _Float16* dA = &L[(t & 3) * 16384 + w * 1024];
        _Float16* dB = dA + 8192;
        const _Float16* sA = a_base + t * 4096;
        const _Float16* sB = b_base + t * 8192;
        gload16(sA,       dA);
        gload16(sA + 512, dA + 512);
        gload16(sB,       dB);
        gload16(sB + 512, dB + 512);
    };

    f32x4 acc[8][4];
#pragma unroll
    for (int i = 0; i < 8; ++i)
#pragma unroll
        for (int j = 0; j < 4; ++j)
#pragma unroll
            for (int e = 0; e < 4; ++e) acc[i][j][e] = 0.f;

    stage(0); stage(1); stage(2);

    const int ar = (wy * 128 + lrow) * 32 + lk * 8;          // + mt*512
    const int br = 8192 + (wx * 64 + lrow) * 32 + lk * 8;    // + nt*512

    auto compute = [&](int kt) {
        const _Float16* Lb = &L[(kt & 3) * 16384];
        f16x8 af[8], bf[4];
#pragma unroll
        for (int mt = 0; mt < 8; ++mt)
            af[mt] = *(const f16x8*)(Lb + ar + mt * 512);
#pragma unroll
        for (int nt = 0; nt < 4; ++nt)
            bf[nt] = *(const f16x8*)(Lb + br + nt * 512);
        __builtin_amdgcn_s_setprio(1);
#pragma unroll
        for (int mt = 0; mt < 8; ++mt)
#pragma unroll
            for (int nt = 0; nt < 4; ++nt)
                acc[mt][nt] = __builtin_amdgcn_mfma_f32_16x16x32_f16(af[mt], bf[nt], acc[mt][nt], 0, 0, 0);
        __builtin_amdgcn_s_setprio(0);
    };

    for (int kt = 0; kt < 14; ++kt) {
        WAITV8();                 // stage(kt) landed (only kt+1,kt+2 younger)
        BAR();
        stage(kt + 3);            // slot (kt-1)&3: all readers passed barrier
        compute(kt);
    }
    WAITV4(); BAR(); compute(14); // stage(15) younger (4 loads)
    WAITV0(); BAR(); compute(15);

    // epilogue
#pragma unroll
    for (int mt = 0; mt < 8; ++mt)
#pragma unroll
        for (int nt = 0; nt < 4; ++nt)
#pragma unroll
            for (int r = 0; r < 4; ++r) {
                size_t row = row0 + wy * 128 + mt * 16 + lk * 4 + r;
                int col = cb * 256 + wx * 64 + nt * 16 + lrow;
                float v = acc[mt][nt][r];
                if (EMODE == 0) {
                    // head-major Qhm[h][row][64]
                    int h = col >> 6;
                    ((_Float16*)Cv)[((size_t)h * NROWS + row) * 64 + (col & 63)] = f2h(v);
                } else {
                    ((float*)Cv)[row * 512 + col] = v + bias[col];
                }
            }
}

// ---------------------------------------------------------------------------
// attn: one block = one (b,h) x 256 Q-rows. K,V staged to LDS once (swizzled
// layouts pre-baked in global). 4 waves x 64 rows. DPP softmax, deferred
// 1/sum. Q read HEAD-MAJOR (full-line 128B/row); AO written K-TILED for
// gemm_o's contiguous staging. grid (16 chunks, 8 h, 16 b); block 256.
// ---------------------------------------------------------------------------
__global__ __launch_bounds__(256)
void attn(const _Float16* __restrict__ Qhm, const _Float16* __restrict__ Kswz,
          const _Float16* __restrict__ Vswz, _Float16* __restrict__ AOt)
{
    __shared__ _Float16 Ks[M_PAD * 64];    // 12KB
    __shared__ _Float16 Vs[64 * 128];      // 16KB
    __shared__ _Float16 Pl[4][16][104];    // 13KB

    const int tid = threadIdx.x;
    const int l = tid & 63, w = tid >> 6;
    const int lrow = l & 15, lk = l >> 4;
    const int chunk = blockIdx.x, h = blockIdx.y, b = blockIdx.z;
    const int bh = b * NH + h;

    {
        const _Float16* Kg = Kswz + (size_t)bh * (M_PAD * 64);
        const _Float16* Vg = Vswz + (size_t)bh * (64 * 128);
#pragma unroll
        for (int i = 0; i < 3; ++i) {
            int c = w * 3 + i;
            gload16(Kg + c * 512 + l * 8, Ks + c * 512);
        }
#pragma unroll
        for (int i = 0; i < 4; ++i) {
            int c = w * 4 + i;
            gload16(Vg + c * 512 + l * 8, Vs + c * 512);
        }
    }

    const size_t row0 = (size_t)b * N_SEQ + chunk * 256 + w * 64;
    f16x8 af[4][2];
    {
        const _Float16* Qb = Qhm + ((size_t)h * NROWS + row0 + lrow) * 64 + lk * 8;
#pragma unroll
        for (int mt = 0; mt < 4; ++mt)
#pragma unroll
            for (int kk = 0; kk < 2; ++kk)
                af[mt][kk] = *(const f16x8*)(Qb + (size_t)mt * 16 * 64 + kk * 32);
    }

    for (int idx = l; idx < 256; idx += 64)
        Pl[w][idx >> 4][80 + (idx & 15)] = (_Float16)0.f;

    __syncthreads();   // drains vmcnt: K/V in LDS

    const bool m4ok = (lrow < 13);
    const int kswz = lrow & 7;

#pragma unroll
    for (int mt = 0; mt < 4; ++mt) {
        f32x4 s[5];
#pragma unroll
        for (int i = 0; i < 5; ++i)
#pragma unroll
            for (int e = 0; e < 4; ++e) s[i][e] = 0.f;
#pragma unroll
        for (int kk = 0; kk < 2; ++kk)
#pragma unroll
            for (int ct = 0; ct < 5; ++ct) {
                f16x8 kf = *(const f16x8*)&Ks[(ct * 16 + lrow) * 64 + (((kk * 4 + lk) ^ kswz) * 8)];
                s[ct] = __builtin_amdgcn_mfma_f32_16x16x32_f16(af[mt][kk], kf, s[ct], 0, 0, 0);
            }

        float rinv[4];
#pragma unroll
        for (int r = 0; r < 4; ++r) {
            float v0 = s[0][r], v1 = s[1][r], v2 = s[2][r], v3 = s[3][r], v4 = s[4][r];
            float mx = fmaxf(fmaxf(v0, v1), fmaxf(v2, v3));
            mx = fmaxf(mx, m4ok ? v4 : -1e30f);
            mx = rmax16(mx);
            float e0 = __expf(v0 - mx), e1 = __expf(v1 - mx);
            float e2 = __expf(v2 - mx), e3 = __expf(v3 - mx);
            float e4 = m4ok ? __expf(v4 - mx) : 0.f;
            float sum = ((e0 + e1) + (e2 + e3)) + e4;
            sum = rsum16(sum);
            rinv[r] = 1.0f / sum;
            int prow = lk * 4 + r;
            Pl[w][prow][lrow]      = f2h(e0);
            Pl[w][prow][16 + lrow] = f2h(e1);
            Pl[w][prow][32 + lrow] = f2h(e2);
            Pl[w][prow][48 + lrow] = f2h(e3);
            Pl[w][prow][64 + lrow] = f2h(e4);
        }

        f32x4 o[4];
#pragma unroll
        for (int i = 0; i < 4; ++i)
#pragma unroll
            for (int e2 = 0; e2 < 4; ++e2) o[i][e2] = 0.f;
#pragma unroll
        for (int kk = 0; kk < 3; ++kk) {
            f16x8 pa = *(const f16x8*)&Pl[w][lrow][kk * 32 + lk * 8];
#pragma unroll
            for (int ctd = 0; ctd < 4; ++ctd) {
                f16x8 vf = *(const f16x8*)&Vs[(ctd * 16 + lrow) * 128 + (((kk * 4 + lk) ^ kswz) * 8)];
                o[ctd] = __builtin_amdgcn_mfma_f32_16x16x32_f16(pa, vf, o[ctd], 0, 0, 0);
            }
        }

        // AO in K-tiled layout AOt[rb][ktc][128][32]
        const size_t rw = row0 + mt * 16 + lk * 4;
#pragma unroll
        for (int ctd = 0; ctd < 4; ++ctd) {
            const int ktc = (h << 1) | (ctd >> 1);
            const int c = ((ctd & 1) << 4) | lrow;
#pragma unroll
            for (int r = 0; r < 4; ++r) {
                size_t g = rw + r;
                AOt[(((g >> 7) * 16 + ktc) * 128 + (g & 127)) * 32 + c] =
                    f2h(o[ctd][r] * rinv[r]);
            }
        }
    }
}

// ---------------------------------------------------------------------------
extern "C" void kernel_launch(void* const* d_in, const int* in_sizes, int n_in,
                              void* d_out, int out_size, void* d_ws, size_t ws_size,
                              hipStream_t stream)
{
    (void)in_sizes; (void)n_in; (void)out_size; (void)ws_size;
    const float* x    = (const float*)d_in[0];
    const float* cond = (const float*)d_in[1];
    const float* Wq   = (const float*)d_in[2];
    const float* Wk   = (const float*)d_in[3];
    const float* Wv   = (const float*)d_in[4];
    const float* Wo   = (const float*)d_in[5];
    const float* bo   = (const float*)d_in[6];

    char* ws = (char*)d_ws;
    _Float16* WqTt = (_Float16*)(ws);                        // 524288
    _Float16* WoTt = (_Float16*)(ws + 524288);               // 524288
    _Float16* Kswz = (_Float16*)(ws + 1048576);              // 1572864
    _Float16* Vswz = (_Float16*)(ws + 2621440);              // 2097152
    _Float16* xhT  = (_Float16*)(ws + 4718592);              // 67108864
    // WkT/WvT alias xhT's head: consumed by kv_proj BEFORE convert overwrites
    _Float16* WkT  = (_Float16*)(ws + 4718592);               // 786432
    _Float16* WvT  = (_Float16*)(ws + 4718592 + 786432);      // 786432
    _Float16* AOt  = xhT;                                     // xhT dead after gemm_q
    // total ws: 71,827,456 bytes (same as previous rounds)
    _Float16* Qhm  = (_Float16*)d_out;                        // dead before gemm_o writes

    prep<<<dim3(16, 24, 2), 256, 0, stream>>>(Wk, Wv, WkT, WvT);
    prep_bt<<<dim3(16, 16, 2), 256, 0, stream>>>(Wq, Wo, WqTt, WoTt);
    kv_proj<<<dim3(8, 16, 2), 256, 0, stream>>>(cond, WkT, WvT, Kswz, Vswz);
    convert_t<<<dim3(2048), 256, 0, stream>>>(x, (f16x8*)xhT, NROWS * 512 / 8);
    gemm_pipe<0><<<dim3(512), 512, 0, stream>>>(xhT, WqTt, Qhm, nullptr);
    attn<<<dim3(16, 8, 16), 256, 0, stream>>>(Qhm, Kswz, Vswz, AOt);
    gemm_pipe<1><<<dim3(512), 512, 0, stream>>>(AOt, WoTt, d_out, bo);
}

// Round 13
// 220.113 us; speedup vs baseline: 1.0608x; 1.0608x over previous
//
#include <hip/hip_runtime.h>

typedef __attribute__((ext_vector_type(8))) _Float16 f16x8;
typedef __attribute__((ext_vector_type(4))) float f32x4;

#define B_SZ   16
#define N_SEQ  4096
#define M_CTX  77
#define M_PAD  96
#define NH     8

__device__ __forceinline__ _Float16 f2h(float x) { return (_Float16)x; }

// async global->LDS, 16B per lane. dst = wave-uniform base; HW writes
// dst + lane*16. Source address is per-lane (pre-swizzled by caller).
__device__ __forceinline__ void gload16(const void* g, void* l) {
    __builtin_amdgcn_global_load_lds(
        (const __attribute__((address_space(1))) unsigned int*)g,
        (__attribute__((address_space(3))) unsigned int*)l, 16, 0, 0);
}

#define BAR()    asm volatile("s_barrier" ::: "memory")
#define WAITV0() asm volatile("s_waitcnt vmcnt(0)" ::: "memory")

// ---- DPP 16-lane butterfly reductions (XOR masks {1,2,7,15} span 0..15) ----
template<int C>
__device__ __forceinline__ float dppf(float x) {
    union { float f; int i; } u, v;
    u.f = x;
    v.i = __builtin_amdgcn_mov_dpp(u.i, C, 0xF, 0xF, true);
    return v.f;
}
__device__ __forceinline__ float rmax16(float x) {
    x = fmaxf(x, dppf<0xB1>(x));    // quad_perm(1,0,3,2)  xor 1
    x = fmaxf(x, dppf<0x4E>(x));    // quad_perm(2,3,0,1)  xor 2
    x = fmaxf(x, dppf<0x141>(x));   // row_half_mirror     xor 7
    x = fmaxf(x, dppf<0x140>(x));   // row_mirror          xor 15
    return x;
}
__device__ __forceinline__ float rsum16(float x) {
    x += dppf<0xB1>(x);
    x += dppf<0x4E>(x);
    x += dppf<0x141>(x);
    x += dppf<0x140>(x);
    return x;
}

// ---------------------------------------------------------------------------
// convert: x fp32 -> x_h f16 (memory-bound, ~201 MB) [R2-proven, 6.1 TB/s]
// ---------------------------------------------------------------------------
__global__ __launch_bounds__(256)
void convert(const float4* __restrict__ x, f16x8* __restrict__ xh, int n8)
{
    int idx = blockIdx.x * 256 + threadIdx.x;
    int stride = gridDim.x * 256;
    for (int i = idx; i < n8; i += stride) {
        float4 a = x[2 * i];
        float4 b = x[2 * i + 1];
        f16x8 o;
        o[0] = f2h(a.x); o[1] = f2h(a.y); o[2] = f2h(a.z); o[3] = f2h(a.w);
        o[4] = f2h(b.x); o[5] = f2h(b.y); o[6] = f2h(b.z); o[7] = f2h(b.w);
        xh[i] = o;
    }
}

// ---------------------------------------------------------------------------
// prep: W [K][512] fp32 -> WT [512][K] f16 (LDS-tiled transpose).
// Wq gets the 1/sqrt(D_HEAD)=0.125 softmax scale folded in.
// ---------------------------------------------------------------------------
__global__ __launch_bounds__(256)
void prep(const float* __restrict__ Wq, const float* __restrict__ Wk,
          const float* __restrict__ Wv, const float* __restrict__ Wo,
          _Float16* __restrict__ WqT, _Float16* __restrict__ WkT,
          _Float16* __restrict__ WvT, _Float16* __restrict__ WoT)
{
    __shared__ float t[32][33];
    const float* W; _Float16* WT; int K; float scale = 1.0f;
    switch (blockIdx.z) {
        case 0:  W = Wq; WT = WqT; K = 512; scale = 0.125f; break;
        case 1:  W = Wk; WT = WkT; K = 768; break;
        case 2:  W = Wv; WT = WvT; K = 768; break;
        default: W = Wo; WT = WoT; K = 512; break;
    }
    const int ky = blockIdx.y;
    if (ky * 32 >= K) return;
    const int nx = blockIdx.x;
    const int tr = threadIdx.x >> 5, tc = threadIdx.x & 31;
#pragma unroll
    for (int i = 0; i < 4; ++i) {
        int kr = tr + i * 8;
        t[kr][tc] = W[(size_t)(ky * 32 + kr) * 512 + nx * 32 + tc];
    }
    __syncthreads();
#pragma unroll
    for (int i = 0; i < 4; ++i) {
        int nr = tr + i * 8;
        WT[(size_t)(nx * 32 + nr) * K + ky * 32 + tc] = f2h(t[tc][nr] * scale);
    }
}

// ---------------------------------------------------------------------------
// kv_proj: writes K and V in BANK-SWIZZLED global layouts (R3-proven):
//   Kswz[bh][m][ ((d>>3)^(m&7))*8 + (d&7) ]   m in 0..95 (zeros >= 77)
//   Vswz[bh][d][ ((m>>3)^(d&7))*8 + (m&7) ]   rows of 128 f16
// grid (8 h, 16 b, 2 kv); block 256 = 4 waves
// ---------------------------------------------------------------------------
__global__ __launch_bounds__(256)
void kv_proj(const float* __restrict__ cond, const _Float16* __restrict__ WkT,
             const _Float16* __restrict__ WvT, _Float16* __restrict__ Kswz,
             _Float16* __restrict__ Vswz)
{
    const int tid = threadIdx.x;
    const int l = tid & 63, w = tid >> 6;
    const int lrow = l & 15, lk = l >> 4;
    const int h = blockIdx.x, b = blockIdx.y, which = blockIdx.z;
    const _Float16* WT = which ? WvT : WkT;
    const float* cb = cond + (size_t)b * M_CTX * 768;

    f32x4 acc[5];
#pragma unroll
    for (int i = 0; i < 5; ++i)
#pragma unroll
        for (int e = 0; e < 4; ++e) acc[i][e] = 0.f;

    const int n = h * 64 + w * 16 + lrow;
    for (int kk = 0; kk < 24; ++kk) {
        f16x8 bfrag = *(const f16x8*)(WT + (size_t)n * 768 + kk * 32 + lk * 8);
#pragma unroll
        for (int rt = 0; rt < 5; ++rt) {
            int m = rt * 16 + lrow;
            f16x8 afrag;
#pragma unroll
            for (int j = 0; j < 8; ++j) afrag[j] = (_Float16)0.f;
            if (m < M_CTX) {
                const float* a = cb + (size_t)m * 768 + kk * 32 + lk * 8;
                float4 f0 = *(const float4*)a;
                float4 f1 = *(const float4*)(a + 4);
                afrag[0] = f2h(f0.x); afrag[1] = f2h(f0.y);
                afrag[2] = f2h(f0.z); afrag[3] = f2h(f0.w);
                afrag[4] = f2h(f1.x); afrag[5] = f2h(f1.y);
                afrag[6] = f2h(f1.z); afrag[7] = f2h(f1.w);
            }
            acc[rt] = __builtin_amdgcn_mfma_f32_16x16x32_f16(afrag, bfrag, acc[rt], 0, 0, 0);
        }
    }

    const int bh = b * NH + h;
    const int d = w * 16 + lrow;
    const int dhi = d >> 3, dlo = d & 7;
    if (which == 0) {
        _Float16* Kb = Kswz + (size_t)bh * (M_PAD * 64);
#pragma unroll
        for (int rt = 0; rt < 5; ++rt)
#pragma unroll
            for (int r = 0; r < 4; ++r) {
                int m = rt * 16 + lk * 4 + r;
                Kb[m * 64 + ((dhi ^ (m & 7)) * 8) + dlo] = f2h(acc[rt][r]);
            }
#pragma unroll
        for (int r = 0; r < 4; ++r) {
            int m = 80 + lk * 4 + r;
            Kb[m * 64 + ((dhi ^ (m & 7)) * 8) + dlo] = (_Float16)0.f;
        }
    } else {
        _Float16* Vb = Vswz + (size_t)bh * (64 * 128);
#pragma unroll
        for (int rt = 0; rt < 5; ++rt)
#pragma unroll
            for (int r = 0; r < 4; ++r) {
                int m = rt * 16 + lk * 4 + r;
                Vb[d * 128 + (((m >> 3) ^ dlo) * 8) + (m & 7)] = f2h(acc[rt][r]);
            }
#pragma unroll
        for (int r = 0; r < 4; ++r) {
            int m = 80 + lk * 4 + r;
            Vb[d * 128 + (((m >> 3) ^ dlo) * 8) + (m & 7)] = (_Float16)0.f;
        }
    }
}

// ---------------------------------------------------------------------------
// gemm_db: C[65536][512] = A[65536][512] @ B (BT[512][512] f16 given).
// gemm512's PROVEN geometry (128x128 tile, BK=64, [128][64] LDS tiles,
// XOR-8 slot involution = 2-way/free banks, pre-swizzled gload16 source)
// + T14 issue-early/wait-late DOUBLE BUFFER:
//   per kt: vmcnt(0)  [waits only residue of stage(kt), issued a full
//           compute-phase earlier] ; s_barrier ; stage(kt+1 -> buf^1) ;
//           16 ds_read_b128 + 32 MFMA from buf.
// WAR: stage(kt+1->buf^1) issues after BAR(kt); all waves past BAR(kt) have
// issued their MFMAs(kt-1), whose lgkmcnt waits forced buf^1 reads complete.
// RAW: vmcnt(0)+barrier. LDS 64KB => 2 resident blocks/CU.
// EMODE 0: C f16; EMODE 1: C fp32 + bias. grid 2048 (XCD-chunked), block 256.
// ---------------------------------------------------------------------------
template<int EMODE>
__global__ __launch_bounds__(256)
void gemm_db(const _Float16* __restrict__ A, const _Float16* __restrict__ BT,
             void* __restrict__ Cv, const float* __restrict__ bias)
{
    __shared__ _Float16 As[2][128 * 64];
    __shared__ _Float16 Bs[2][128 * 64];

    const int bid = blockIdx.x;
    const int wg = (bid & 7) * 256 + (bid >> 3);
    const int rb = wg >> 2;
    const int cb = wg & 3;
    const size_t row0 = (size_t)rb * 128;
    const int col0 = cb * 128;

    const int tid = threadIdx.x;
    const int l = tid & 63;
    const int w = tid >> 6;
    const int wy = w >> 1, wx = w & 1;
    const int lrow = l & 15, lk = l >> 4;

    f32x4 acc[4][4];
#pragma unroll
    for (int i = 0; i < 4; ++i)
#pragma unroll
        for (int j = 0; j < 4; ++j)
#pragma unroll
            for (int e = 0; e < 4; ++e) acc[i][j][e] = 0.f;

    const int srow = l >> 3;                       // row within 8-row segment
    const int sslot = (l & 7) ^ (srow & 7);        // pre-swizzled source slot
    const _Float16* a_src0 = A + (row0 + (size_t)(w * 32 + srow)) * 512 + sslot * 8;
    const _Float16* b_src0 = BT + ((size_t)(col0 + w * 32 + srow)) * 512 + sslot * 8;

    auto stage = [&](int kt) {
        const int buf = kt & 1;
        const _Float16* ak = a_src0 + kt * 64;
        const _Float16* bk = b_src0 + kt * 64;
#pragma unroll
        for (int s = 0; s < 4; ++s) {
            gload16(ak + (size_t)s * 8 * 512, &As[buf][(w * 4 + s) * 512]);
            gload16(bk + (size_t)s * 8 * 512, &Bs[buf][(w * 4 + s) * 512]);
        }
    };

    stage(0);                          // prologue: buf0 in flight

    for (int kt = 0; kt < 8; ++kt) {
        const int buf = kt & 1;
        WAITV0();                      // stage(kt) landed (issued iter kt-1)
        BAR();                         // collective; also WAR fence
        if (kt < 7) stage(kt + 1);     // -> buf^1, overlaps compute below

#pragma unroll
        for (int kk = 0; kk < 2; ++kk) {
            f16x8 af[4], bf[4];
#pragma unroll
            for (int mt = 0; mt < 4; ++mt) {
                int R = wy * 64 + mt * 16 + lrow;
                int p = (kk * 4 + lk) ^ (lrow & 7);
                af[mt] = *(const f16x8*)&As[buf][R * 64 + p * 8];
            }
#pragma unroll
            for (int nt = 0; nt < 4; ++nt) {
                int R = wx * 64 + nt * 16 + lrow;
                int p = (kk * 4 + lk) ^ (lrow & 7);
                bf[nt] = *(const f16x8*)&Bs[buf][R * 64 + p * 8];
            }
            __builtin_amdgcn_s_setprio(1);
#pragma unroll
            for (int mt = 0; mt < 4; ++mt)
#pragma unroll
                for (int nt = 0; nt < 4; ++nt)
                    acc[mt][nt] = __builtin_amdgcn_mfma_f32_16x16x32_f16(af[mt], bf[nt], acc[mt][nt], 0, 0, 0);
            __builtin_amdgcn_s_setprio(0);
        }
    }

#pragma unroll
    for (int mt = 0; mt < 4; ++mt)
#pragma unroll
        for (int nt = 0; nt < 4; ++nt)
#pragma unroll
            for (int r = 0; r < 4; ++r) {
                size_t row = row0 + wy * 64 + mt * 16 + lk * 4 + r;
                int col = col0 + wx * 64 + nt * 16 + lrow;
                float v = acc[mt][nt][r];
                if (EMODE == 0) {
                    ((_Float16*)Cv)[row * 512 + col] = f2h(v);
                } else {
                    ((float*)Cv)[row * 512 + col] = v + bias[col];
                }
            }
}

// ---------------------------------------------------------------------------
// attn (R3-proven): one block = one (b,h) x 256 Q-rows. K,V staged to LDS
// once via gload16 (swizzled layouts pre-baked in global). 4 waves x 64 rows.
// DPP softmax reductions, deferred 1/sum in the O epilogue.
// grid (16 chunks, 8 h, 16 b); block 256.
// ---------------------------------------------------------------------------
__global__ __launch_bounds__(256)
void attn(const _Float16* __restrict__ Q, const _Float16* __restrict__ Kswz,
          const _Float16* __restrict__ Vswz, _Float16* __restrict__ AO)
{
    __shared__ _Float16 Ks[M_PAD * 64];    // 12KB: row m, slot s at s^(m&7)
    __shared__ _Float16 Vs[64 * 128];      // 16KB: row d, slot s at s^(d&7)
    __shared__ _Float16 Pl[4][16][104];    // 13KB: per-wave P tile

    const int tid = threadIdx.x;
    const int l = tid & 63, w = tid >> 6;
    const int lrow = l & 15, lk = l >> 4;
    const int chunk = blockIdx.x, h = blockIdx.y, b = blockIdx.z;
    const int bh = b * NH + h;

    {
        const _Float16* Kg = Kswz + (size_t)bh * (M_PAD * 64);
        const _Float16* Vg = Vswz + (size_t)bh * (64 * 128);
#pragma unroll
        for (int i = 0; i < 3; ++i) {
            int c = w * 3 + i;
            gload16(Kg + c * 512 + l * 8, Ks + c * 512);
        }
#pragma unroll
        for (int i = 0; i < 4; ++i) {
            int c = w * 4 + i;
            gload16(Vg + c * 512 + l * 8, Vs + c * 512);
        }
    }

    const size_t row0 = (size_t)b * N_SEQ + chunk * 256 + w * 64;
    f16x8 af[4][2];
    {
        const _Float16* Qb = Q + (row0 + lrow) * 512 + h * 64 + lk * 8;
#pragma unroll
        for (int mt = 0; mt < 4; ++mt)
#pragma unroll
            for (int kk = 0; kk < 2; ++kk)
                af[mt][kk] = *(const f16x8*)(Qb + (size_t)mt * 16 * 512 + kk * 32);
    }

    for (int idx = l; idx < 256; idx += 64)
        Pl[w][idx >> 4][80 + (idx & 15)] = (_Float16)0.f;

    __syncthreads();   // drains vmcnt: K/V in LDS

    const bool m4ok = (lrow < 13);
    const int kswz = lrow & 7;

#pragma unroll
    for (int mt = 0; mt < 4; ++mt) {
        f32x4 s[5];
#pragma unroll
        for (int i = 0; i < 5; ++i)
#pragma unroll
            for (int e = 0; e < 4; ++e) s[i][e] = 0.f;
#pragma unroll
        for (int kk = 0; kk < 2; ++kk)
#pragma unroll
            for (int ct = 0; ct < 5; ++ct) {
                f16x8 kf = *(const f16x8*)&Ks[(ct * 16 + lrow) * 64 + (((kk * 4 + lk) ^ kswz) * 8)];
                s[ct] = __builtin_amdgcn_mfma_f32_16x16x32_f16(af[mt][kk], kf, s[ct], 0, 0, 0);
            }

        float rinv[4];
#pragma unroll
        for (int r = 0; r < 4; ++r) {
            float v0 = s[0][r], v1 = s[1][r], v2 = s[2][r], v3 = s[3][r], v4 = s[4][r];
            float mx = fmaxf(fmaxf(v0, v1), fmaxf(v2, v3));
            mx = fmaxf(mx, m4ok ? v4 : -1e30f);
            mx = rmax16(mx);
            float e0 = __expf(v0 - mx), e1 = __expf(v1 - mx);
            float e2 = __expf(v2 - mx), e3 = __expf(v3 - mx);
            float e4 = m4ok ? __expf(v4 - mx) : 0.f;
            float sum = ((e0 + e1) + (e2 + e3)) + e4;
            sum = rsum16(sum);
            rinv[r] = 1.0f / sum;
            int prow = lk * 4 + r;
            Pl[w][prow][lrow]      = f2h(e0);
            Pl[w][prow][16 + lrow] = f2h(e1);
            Pl[w][prow][32 + lrow] = f2h(e2);
            Pl[w][prow][48 + lrow] = f2h(e3);
            Pl[w][prow][64 + lrow] = f2h(e4);
        }

        f32x4 o[4];
#pragma unroll
        for (int i = 0; i < 4; ++i)
#pragma unroll
            for (int e2 = 0; e2 < 4; ++e2) o[i][e2] = 0.f;
#pragma unroll
        for (int kk = 0; kk < 3; ++kk) {
            f16x8 pa = *(const f16x8*)&Pl[w][lrow][kk * 32 + lk * 8];
#pragma unroll
            for (int ctd = 0; ctd < 4; ++ctd) {
                f16x8 vf = *(const f16x8*)&Vs[(ctd * 16 + lrow) * 128 + (((kk * 4 + lk) ^ kswz) * 8)];
                o[ctd] = __builtin_amdgcn_mfma_f32_16x16x32_f16(pa, vf, o[ctd], 0, 0, 0);
            }
        }

        const size_t rw = row0 + mt * 16 + lk * 4;
#pragma unroll
        for (int ctd = 0; ctd < 4; ++ctd)
#pragma unroll
            for (int r = 0; r < 4; ++r)
                AO[(rw + r) * 512 + h * 64 + ctd * 16 + lrow] = f2h(o[ctd][r] * rinv[r]);
    }
}

// ---------------------------------------------------------------------------
extern "C" void kernel_launch(void* const* d_in, const int* in_sizes, int n_in,
                              void* d_out, int out_size, void* d_ws, size_t ws_size,
                              hipStream_t stream)
{
    (void)in_sizes; (void)n_in; (void)out_size; (void)ws_size;
    const float* x    = (const float*)d_in[0];
    const float* cond = (const float*)d_in[1];
    const float* Wq   = (const float*)d_in[2];
    const float* Wk   = (const float*)d_in[3];
    const float* Wv   = (const float*)d_in[4];
    const float* Wo   = (const float*)d_in[5];
    const float* bo   = (const float*)d_in[6];

    char* ws = (char*)d_ws;
    _Float16* WqT  = (_Float16*)(ws);                        // 524288
    _Float16* WoT  = (_Float16*)(ws + 524288);               // 524288
    _Float16* Kswz = (_Float16*)(ws + 1048576);              // 1572864
    _Float16* Vswz = (_Float16*)(ws + 2621440);              // 2097152
    _Float16* xh   = (_Float16*)(ws + 4718592);              // 67108864
    // WkT/WvT alias xh's head: consumed by kv_proj BEFORE convert overwrites
    _Float16* WkT  = (_Float16*)(ws + 4718592);              // 786432
    _Float16* WvT  = (_Float16*)(ws + 4718592 + 786432);     // 786432
    _Float16* AO   = xh;                                     // xh dead after gemm_q
    // total ws: 71,827,456 bytes (same as previous rounds)
    _Float16* Qf   = (_Float16*)d_out;                       // dead before gemm_o writes

    prep<<<dim3(16, 24, 4), 256, 0, stream>>>(Wq, Wk, Wv, Wo, WqT, WkT, WvT, WoT);
    kv_proj<<<dim3(8, 16, 2), 256, 0, stream>>>(cond, WkT, WvT, Kswz, Vswz);
    convert<<<dim3(2048), 256, 0, stream>>>((const float4*)x, (f16x8*)xh, 16 * 4096 * 512 / 8);
    gemm_db<0><<<dim3(2048), 256, 0, stream>>>(xh, WqT, Qf, nullptr);
    attn<<<dim3(16, 8, 16), 256, 0, stream>>>(Qf, Kswz, Vswz, AO);
    gemm_db<1><<<dim3(2048), 256, 0, stream>>>(AO, WoT, d_out, bo);
}